// Round 1
// baseline (480.050 us; speedup 1.0000x reference)
//
#include <hip/hip_runtime.h>
#include <cstdint>
#include <cstddef>

#define S_LEN 4096
#define NB 8
#define NH 12
#define DMODEL 768
#define DHEAD 64
#define M_TOT (NB * S_LEN)      /* 32768 */
#define INV_SQRT_DH 0.125f

#define BM 128
#define BN 128
#define BK 64

typedef __attribute__((ext_vector_type(4))) float f32x4;
typedef __attribute__((ext_vector_type(8))) short bf16x8;

__device__ inline float bf2f(unsigned short h) {
    union { unsigned int u; float f; } v; v.u = ((unsigned int)h) << 16; return v.f;
}
__device__ inline unsigned short f2bf(float f) {
    union { float f; unsigned int u; } v; v.f = f;
    unsigned int r = v.u + 0x7FFFu + ((v.u >> 16) & 1u);
    return (unsigned short)(r >> 16);
}

__device__ inline void gload_lds16(const unsigned short* gp, void* lp) {
    __builtin_amdgcn_global_load_lds((const __attribute__((address_space(1))) void*)gp,
                                     (__attribute__((address_space(3))) void*)lp,
                                     16, 0, 0);
}

// ---------------- prep kernels ----------------
__global__ void cvt_f32_bf16(const float* __restrict__ src, unsigned short* __restrict__ dst, int n) {
    int i = (blockIdx.x * blockDim.x + threadIdx.x) * 4;
    if (i + 3 < n) {
        float4 v = *(const float4*)(src + i);
        ushort4 o;
        o.x = f2bf(v.x); o.y = f2bf(v.y); o.z = f2bf(v.z); o.w = f2bf(v.w);
        *(ushort4*)(dst + i) = o;
    } else {
        for (; i < n; ++i) dst[i] = f2bf(src[i]);
    }
}

__global__ void wqa_pad(const float* __restrict__ w, unsigned short* __restrict__ dst) {
    int i = blockIdx.x * blockDim.x + threadIdx.x;   // 16*768 threads
    if (i < 16 * DMODEL) {
        int h = i / DMODEL;
        dst[i] = (h < NH) ? f2bf(w[i]) : (unsigned short)0;
    }
}

__global__ void bias_cat(const float* __restrict__ b0, const float* __restrict__ b1, float* __restrict__ dst) {
    int i = blockIdx.x * blockDim.x + threadIdx.x;
    if (i < 2 * DMODEL) dst[i] = (i < DMODEL) ? b0[i] : b1[i - DMODEL];
}

// ---------------- main GEMM (m97 structure) ----------------
// C[M][N] = A[M][K] @ Bw[N][K]^T (+bias) ; mode0: bf16 out, mode1: f32 out + resid
__global__ __launch_bounds__(256) void gemm_bt(
    const unsigned short* __restrict__ A, int lda,
    const unsigned short* __restrict__ Bw, int ldb,
    const float* __restrict__ bias,
    unsigned short* __restrict__ outBf, int ldoBf,
    float* __restrict__ outF, int ldoF,
    const unsigned short* __restrict__ resid, int ldr,
    int K, int ntile, int mode)
{
    __shared__ __align__(16) unsigned short lA[BM * BK];
    __shared__ __align__(16) unsigned short lB[BN * BK];

    int bidn = blockIdx.x % ntile;
    int bidm = blockIdx.x / ntile;
    int m0 = bidm * BM, n0 = bidn * BN;

    int t = threadIdx.x;
    int w = t >> 6;
    int lane = t & 63;
    int lr = lane & 15, lk = lane >> 4;
    int wr = w >> 1, wc = w & 1;

    f32x4 acc[4][4];
#pragma unroll
    for (int m = 0; m < 4; ++m)
#pragma unroll
        for (int n = 0; n < 4; ++n)
            acc[m][n] = (f32x4){0.f, 0.f, 0.f, 0.f};

    int sRow = t >> 3;           // 0..31
    int sCol = (t & 7) * 8;      // element offset in K

    int nsteps = K / BK;
    for (int ks = 0; ks < nsteps; ++ks) {
        int k0 = ks * BK;
#pragma unroll
        for (int i = 0; i < 4; ++i) {
            const unsigned short* gp = A + (size_t)(m0 + i * 32 + sRow) * lda + (k0 + sCol);
            gload_lds16(gp, (char*)lA + i * 4096 + w * 1024);
        }
#pragma unroll
        for (int i = 0; i < 4; ++i) {
            const unsigned short* gp = Bw + (size_t)(n0 + i * 32 + sRow) * ldb + (k0 + sCol);
            gload_lds16(gp, (char*)lB + i * 4096 + w * 1024);
        }
        __syncthreads();   // drains vmcnt(0): staged tiles visible
#pragma unroll
        for (int h = 0; h < 2; ++h) {
            bf16x8 af[4], bfr[4];
#pragma unroll
            for (int m = 0; m < 4; ++m)
                af[m] = *(const bf16x8*)&lA[(wr * 64 + m * 16 + lr) * BK + h * 32 + lk * 8];
#pragma unroll
            for (int n = 0; n < 4; ++n)
                bfr[n] = *(const bf16x8*)&lB[(wc * 64 + n * 16 + lr) * BK + h * 32 + lk * 8];
#pragma unroll
            for (int m = 0; m < 4; ++m)
#pragma unroll
                for (int n = 0; n < 4; ++n)
                    acc[m][n] = __builtin_amdgcn_mfma_f32_16x16x32_bf16(af[m], bfr[n], acc[m][n], 0, 0, 0);
        }
        __syncthreads();   // protect LDS before next stage
    }

    // epilogue: C/D layout col=lane&15, row=4*(lane>>4)+reg  [m89]
#pragma unroll
    for (int m = 0; m < 4; ++m) {
        int row = m0 + wr * 64 + m * 16 + lk * 4;
#pragma unroll
        for (int n = 0; n < 4; ++n) {
            int col = n0 + wc * 64 + n * 16 + lr;
            float bv = bias[col];
#pragma unroll
            for (int r = 0; r < 4; ++r) {
                int gr = row + r;
                float v = acc[m][n][r] + bv;
                if (mode == 0) {
                    outBf[(size_t)gr * ldoBf + col] = f2bf(v);
                } else {
                    v += bf2f(resid[(size_t)gr * ldr + col]);
                    outF[(size_t)gr * ldoF + col] = v;
                }
            }
        }
    }
}

// ---------------- qfs logits: [M,16(12)] = q @ Wqa^T  ----------------
__global__ __launch_bounds__(256) void qfs_kernel(
    const unsigned short* __restrict__ q, int ldq,
    const unsigned short* __restrict__ wqa,   // [16][768] bf16, rows >=12 zero
    const float* __restrict__ bqa,
    const float* __restrict__ mask,           // [B][S]
    float* __restrict__ qfs)                  // [B*H][S]
{
    int t = threadIdx.x;
    int w = t >> 6, lane = t & 63;
    int lr = lane & 15, lk = lane >> 4;
    int m0 = blockIdx.x * 64 + w * 16;

    f32x4 acc = (f32x4){0.f, 0.f, 0.f, 0.f};
    for (int k0 = 0; k0 < DMODEL; k0 += 32) {
        bf16x8 a = *(const bf16x8*)&q[(size_t)(m0 + lr) * ldq + k0 + lk * 8];
        bf16x8 b = *(const bf16x8*)&wqa[lr * DMODEL + k0 + lk * 8];
        acc = __builtin_amdgcn_mfma_f32_16x16x32_bf16(a, b, acc, 0, 0, 0);
    }
    if (lr < NH) {
        float bv = bqa[lr];
#pragma unroll
        for (int r = 0; r < 4; ++r) {
            int m = m0 + lk * 4 + r;
            int b_ = m >> 12;
            int s = m & (S_LEN - 1);
            qfs[((size_t)b_ * NH + lr) * S_LEN + s] = acc[r] * INV_SQRT_DH + bv + mask[b_ * S_LEN + s];
        }
    }
}

// ---------------- softmax-pool: pooled[bh][d] = sum_s softmax(logits)[s] * x[b,s,h*64+d] ----------------
__global__ __launch_bounds__(1024) void pool_kernel(
    const float* __restrict__ logits,          // [B*H][S]
    const unsigned short* __restrict__ x, int ldx,
    float* __restrict__ pooled)                // [B*H][64]
{
    int bh = blockIdx.x;
    int b = bh / NH, h = bh % NH;
    const float* lg = logits + (size_t)bh * S_LEN;
    int t = threadIdx.x;

    __shared__ float redm[16];
    __shared__ float reds[16];
    __shared__ float part[16][64];

    float mx = -1e30f;
    for (int s = t; s < S_LEN; s += 1024) mx = fmaxf(mx, lg[s]);
#pragma unroll
    for (int off = 32; off; off >>= 1) mx = fmaxf(mx, __shfl_xor(mx, off));
    if ((t & 63) == 0) redm[t >> 6] = mx;
    __syncthreads();
    float bmax = redm[0];
#pragma unroll
    for (int i = 1; i < 16; ++i) bmax = fmaxf(bmax, redm[i]);

    float sm = 0.f;
    for (int s = t; s < S_LEN; s += 1024) sm += __expf(lg[s] - bmax);
#pragma unroll
    for (int off = 32; off; off >>= 1) sm += __shfl_xor(sm, off);
    if ((t & 63) == 0) reds[t >> 6] = sm;
    __syncthreads();
    float bsum = 0.f;
#pragma unroll
    for (int i = 0; i < 16; ++i) bsum += reds[i];

    int d = t & 63, g = t >> 6;   // 16 s-groups
    const unsigned short* xp = x + (size_t)b * S_LEN * ldx + h * DHEAD + d;
    float acc = 0.f;
    for (int s = g; s < S_LEN; s += 16)
        acc += __expf(lg[s] - bmax) * bf2f(xp[(size_t)s * ldx]);
    part[g][d] = acc;
    __syncthreads();
    if (t < 64) {
        float v = 0.f;
#pragma unroll
        for (int i = 0; i < 16; ++i) v += part[i][t];
        pooled[(size_t)bh * DHEAD + t] = v / bsum;
    }
}

// ---------------- qks logits: qks[b,h,s] = (k[b,s,h*64:].pooled_q[b,h,:])*inv + mask ----------------
__global__ __launch_bounds__(256) void qks_kernel(
    const unsigned short* __restrict__ kmat, int ldk,
    const float* __restrict__ pooled_q,
    const float* __restrict__ mask,
    float* __restrict__ qks)
{
    int b = blockIdx.y;
    int s0 = blockIdx.x * 16;
    __shared__ float pq[NH][DHEAD + 4];
    int t = threadIdx.x;
    for (int i = t; i < NH * DHEAD; i += 256)
        pq[i >> 6][i & 63] = pooled_q[(size_t)b * NH * DHEAD + i];
    __syncthreads();
    int h = t & 15, sl = t >> 4;
    if (h < NH) {
        int s = s0 + sl;
        const unsigned short* kp = kmat + (size_t)(b * S_LEN + s) * ldk + h * DHEAD;
        float acc = 0.f;
#pragma unroll
        for (int c = 0; c < 8; ++c) {
            bf16x8 v = *(const bf16x8*)&kp[c * 8];
#pragma unroll
            for (int j = 0; j < 8; ++j)
                acc += bf2f((unsigned short)v[j]) * pq[h][c * 8 + j];
        }
        qks[((size_t)b * NH + h) * S_LEN + s] = acc * INV_SQRT_DH + mask[b * S_LEN + s];
    }
}

// ---------------- gate: gq[m,k] = q[m,k] * pooled_k[b(m), k/64, k%64] ----------------
__global__ __launch_bounds__(256) void gate_kernel(
    const unsigned short* __restrict__ q, int ldq,
    const float* __restrict__ pooled_k,
    unsigned short* __restrict__ gq)
{
    int i = blockIdx.x * blockDim.x + threadIdx.x;     // one per 8 elems
    int m = i / (DMODEL / 8);
    int kc = (i % (DMODEL / 8)) * 8;
    int b = m >> 12;
    int h = kc >> 6;
    bf16x8 v = *(const bf16x8*)&q[(size_t)m * ldq + kc];
    const float* pk = pooled_k + ((size_t)b * NH + h) * DHEAD + (kc & 63);
    bf16x8 o;
#pragma unroll
    for (int j = 0; j < 8; ++j)
        o[j] = (short)f2bf(bf2f((unsigned short)v[j]) * pk[j]);
    *(bf16x8*)&gq[(size_t)m * DMODEL + kc] = o;
}

// ---------------- launch ----------------
extern "C" void kernel_launch(void* const* d_in, const int* in_sizes, int n_in,
                              void* d_out, int out_size, void* d_ws, size_t ws_size,
                              hipStream_t stream) {
    const float* hs   = (const float*)d_in[0];
    const float* mask = (const float*)d_in[1];
    const float* Wq   = (const float*)d_in[2];
    const float* bq   = (const float*)d_in[3];
    const float* Wqa  = (const float*)d_in[4];
    const float* bqa  = (const float*)d_in[5];
    const float* Wk   = (const float*)d_in[6];
    const float* bk   = (const float*)d_in[7];
    const float* Wt   = (const float*)d_in[8];
    const float* bt   = (const float*)d_in[9];
    float* out = (float*)d_out;

    char* ws = (char*)d_ws;
    unsigned short* qk_bf  = (unsigned short*)(ws);                   // [32768][1536] bf16 (q|k)
    unsigned short* hs_bf  = (unsigned short*)(ws + 100663296);       // [32768][768]  (reused as gq)
    unsigned short* Wqk_bf = (unsigned short*)(ws + 150994944);       // [1536][768]
    unsigned short* Wt_bf  = (unsigned short*)(ws + 153354240);       // [768][768]
    unsigned short* Wqa_bf = (unsigned short*)(ws + 154533888);       // [16][768]
    float* bqk      = (float*)(ws + 154558464);                       // [1536]
    float* qfs      = (float*)(ws + 154564608);                       // [96][4096]
    float* qks      = (float*)(ws + 156137472);                       // [96][4096]
    float* pooled_q = (float*)(ws + 157710336);                       // [96][64]
    float* pooled_k = (float*)(ws + 157734912);                       // [96][64]

    int nHs = M_TOT * DMODEL;        // 25165824
    int nW  = DMODEL * DMODEL;       // 589824

    cvt_f32_bf16<<<nHs / 4 / 256, 256, 0, stream>>>(hs, hs_bf, nHs);
    cvt_f32_bf16<<<nW / 4 / 256, 256, 0, stream>>>(Wq, Wqk_bf, nW);
    cvt_f32_bf16<<<nW / 4 / 256, 256, 0, stream>>>(Wk, Wqk_bf + nW, nW);
    cvt_f32_bf16<<<nW / 4 / 256, 256, 0, stream>>>(Wt, Wt_bf, nW);
    wqa_pad<<<(16 * DMODEL) / 256, 256, 0, stream>>>(Wqa, Wqa_bf);
    bias_cat<<<6, 256, 0, stream>>>(bq, bk, bqk);

    // q|k projection: M=32768, N=1536, K=768
    gemm_bt<<<(M_TOT / BM) * 12, 256, 0, stream>>>(
        hs_bf, DMODEL, Wqk_bf, DMODEL, bqk,
        qk_bf, 2 * DMODEL, nullptr, 0, nullptr, 0,
        DMODEL, 12, 0);

    qfs_kernel<<<M_TOT / 64, 256, 0, stream>>>(qk_bf, 2 * DMODEL, Wqa_bf, bqa, mask, qfs);
    pool_kernel<<<NB * NH, 1024, 0, stream>>>(qfs, qk_bf, 2 * DMODEL, pooled_q);
    qks_kernel<<<dim3(S_LEN / 16, NB), 256, 0, stream>>>(qk_bf + DMODEL, 2 * DMODEL, pooled_q, mask, qks);
    pool_kernel<<<NB * NH, 1024, 0, stream>>>(qks, qk_bf + DMODEL, 2 * DMODEL, pooled_k);

    unsigned short* gq = hs_bf;  // hs_bf dead after first GEMM
    gate_kernel<<<(M_TOT * (DMODEL / 8)) / 256, 256, 0, stream>>>(qk_bf, 2 * DMODEL, pooled_k, gq);

    // out = gq @ Wt^T + bt + q : M=32768, N=768, K=768
    gemm_bt<<<(M_TOT / BM) * 6, 256, 0, stream>>>(
        gq, DMODEL, Wt_bf, DMODEL, bt,
        nullptr, 0, out, DMODEL, qk_bf, 2 * DMODEL,
        DMODEL, 6, 1);
}

// Round 2
// 378.204 us; speedup vs baseline: 1.2693x; 1.2693x over previous
//
#include <hip/hip_runtime.h>
#include <cstdint>
#include <cstddef>

#define S_LEN 4096
#define NB 8
#define NH 12
#define DMODEL 768
#define DHEAD 64
#define M_TOT (NB * S_LEN)      /* 32768 */
#define INV_SQRT_DH 0.125f

typedef __attribute__((ext_vector_type(4))) float f32x4;
typedef __attribute__((ext_vector_type(8))) short bf16x8;

__device__ inline float bf2f(unsigned short h) {
    union { unsigned int u; float f; } v; v.u = ((unsigned int)h) << 16; return v.f;
}
__device__ inline unsigned short f2bf(float f) {
    union { float f; unsigned int u; } v; v.f = f;
    unsigned int r = v.u + 0x7FFFu + ((v.u >> 16) & 1u);
    return (unsigned short)(r >> 16);
}

__device__ inline void gload_lds16(const unsigned short* gp, void* lp) {
    __builtin_amdgcn_global_load_lds((const __attribute__((address_space(1))) void*)gp,
                                     (__attribute__((address_space(3))) void*)lp,
                                     16, 0, 0);
}

// ---------------- prep kernels ----------------
__global__ void cvt_f32_bf16(const float* __restrict__ src, unsigned short* __restrict__ dst, int n) {
    int i = (blockIdx.x * blockDim.x + threadIdx.x) * 4;
    if (i + 3 < n) {
        float4 v = *(const float4*)(src + i);
        ushort4 o;
        o.x = f2bf(v.x); o.y = f2bf(v.y); o.z = f2bf(v.z); o.w = f2bf(v.w);
        *(ushort4*)(dst + i) = o;
    }
}

// one launch for all small weight/bias prep
__global__ void prep_misc(const float* __restrict__ Wq, const float* __restrict__ Wk,
                          const float* __restrict__ Wt, const float* __restrict__ Wqa,
                          const float* __restrict__ bq, const float* __restrict__ bk,
                          unsigned short* __restrict__ Wqk_bf, unsigned short* __restrict__ Wt_bf,
                          unsigned short* __restrict__ Wqa_bf, float* __restrict__ bqk) {
    int bid = blockIdx.x;
    int t = threadIdx.x;
    if (bid < 1728) {
        const float* src = (bid < 576) ? Wq : ((bid < 1152) ? Wk : Wt);
        unsigned short* dst = (bid < 576) ? Wqk_bf : ((bid < 1152) ? (Wqk_bf + DMODEL * DMODEL) : Wt_bf);
        int off = (bid % 576) * 1024 + t * 4;
        float4 v = *(const float4*)(src + off);
        ushort4 o;
        o.x = f2bf(v.x); o.y = f2bf(v.y); o.z = f2bf(v.z); o.w = f2bf(v.w);
        *(ushort4*)(dst + off) = o;
    } else if (bid < 1740) {
        int off = (bid - 1728) * 1024 + t * 4;   // 16*768 = 12288 elems
        int h = off / DMODEL;
        ushort4 o = {0, 0, 0, 0};
        if (h < NH) {
            float4 v = *(const float4*)(Wqa + off);
            o.x = f2bf(v.x); o.y = f2bf(v.y); o.z = f2bf(v.z); o.w = f2bf(v.w);
        }
        *(ushort4*)(Wqa_bf + off) = o;
    } else {
        int off = (bid - 1740) * 1024 + t * 4;
        if (off < 2 * DMODEL) {
            const float* src = (off < DMODEL) ? (bq + off) : (bk + off - DMODEL);
            *(float4*)(bqk + off) = *(const float4*)src;
        }
    }
}

// ---------------- 256x256 8-phase GEMM ----------------
// C[M][N] = A[M][768] @ Bw[N][768]^T + bias ; MODE0: bf16 out, MODE1: f32 out + resid
#define PH_MID() do { __builtin_amdgcn_s_barrier(); \
    asm volatile("s_waitcnt lgkmcnt(0)"); \
    __builtin_amdgcn_sched_barrier(0); \
    __builtin_amdgcn_s_setprio(1); } while (0)
#define PH_END() do { __builtin_amdgcn_s_setprio(0); \
    __builtin_amdgcn_s_barrier(); } while (0)

#define STG_A(q, kt, BO) gload_lds16(pA + (size_t)((q) * 64) * 768 + (kt) * 64, \
                                     lds + (BO) + (q) * 8192 + wOff)
#define STG_B(q, kt, BO) gload_lds16(pB + (size_t)((q) * 64) * 768 + (kt) * 64, \
                                     lds + (BO) + 32768 + (q) * 8192 + wOff)

#define LD_A(mh, BO) do { _Pragma("unroll") for (int mm = 0; mm < 4; ++mm) { \
    a[mm][0] = *(const bf16x8*)(lds + (BO) + aRd0 + ((mh) * 4 + mm) * 2048); \
    a[mm][1] = *(const bf16x8*)(lds + (BO) + aRd1 + ((mh) * 4 + mm) * 2048); } } while (0)
#define LD_B(nh, BO) do { _Pragma("unroll") for (int nn = 0; nn < 2; ++nn) { \
    b[(nh) * 2 + nn][0] = *(const bf16x8*)(lds + (BO) + bRd0 + ((nh) * 2 + nn) * 2048); \
    b[(nh) * 2 + nn][1] = *(const bf16x8*)(lds + (BO) + bRd1 + ((nh) * 2 + nn) * 2048); } } while (0)
#define MFMAQ(mh, nh) do { _Pragma("unroll") for (int mm = 0; mm < 4; ++mm) \
    _Pragma("unroll") for (int nn = 0; nn < 2; ++nn) { \
        acc[(mh) * 4 + mm][(nh) * 2 + nn] = __builtin_amdgcn_mfma_f32_16x16x32_bf16( \
            a[mm][0], b[(nh) * 2 + nn][0], acc[(mh) * 4 + mm][(nh) * 2 + nn], 0, 0, 0); \
        acc[(mh) * 4 + mm][(nh) * 2 + nn] = __builtin_amdgcn_mfma_f32_16x16x32_bf16( \
            a[mm][1], b[(nh) * 2 + nn][1], acc[(mh) * 4 + mm][(nh) * 2 + nn], 0, 0, 0); } } while (0)

template<int MODE>
__global__ __launch_bounds__(512, 2) void gemm8(
    const unsigned short* __restrict__ A,
    const unsigned short* __restrict__ Bw,
    const float* __restrict__ bias,
    unsigned short* __restrict__ outBf, int ldoBf,
    float* __restrict__ outF,
    const unsigned short* __restrict__ resid, int ldr,
    int ntn)
{
    __shared__ __align__(16) char lds[131072];

    int nwg = gridDim.x;
    int bid = blockIdx.x;
    int cpx = nwg >> 3;                        // nwg % 8 == 0 for both launches
    int swz = (bid & 7) * cpx + (bid >> 3);
    int bidn = swz % ntn, bidm = swz / ntn;
    int m0 = bidm * 256, n0 = bidn * 256;

    int t = threadIdx.x;
    int w = t >> 6, lane = t & 63;
    int lr = lane & 15, lk = lane >> 4;
    int wr = w >> 2, wc = w & 3;
    int wOff = w << 10;

    // stage source bases (pre-swizzled global column block: blk ^= row&7)
    int srow = t >> 3;
    int sblk = (t & 7) ^ (srow & 7);
    const unsigned short* pA = A + (size_t)(m0 + srow) * 768 + sblk * 8;
    const unsigned short* pB = Bw + (size_t)(n0 + srow) * 768 + sblk * 8;

    // LDS read bases (bytes); row&7 == lr&7 for all frags
    int sx = lr & 7;
    int aRd0 = (wr * 128 + lr) * 128 + ((0 + lk) ^ sx) * 16;
    int aRd1 = (wr * 128 + lr) * 128 + ((4 + lk) ^ sx) * 16;
    int bRd0 = 32768 + (wc * 64 + lr) * 128 + ((0 + lk) ^ sx) * 16;
    int bRd1 = 32768 + (wc * 64 + lr) * 128 + ((4 + lk) ^ sx) * 16;

    f32x4 acc[8][4];
#pragma unroll
    for (int m = 0; m < 8; ++m)
#pragma unroll
        for (int n = 0; n < 4; ++n)
            acc[m][n] = (f32x4){0.f, 0.f, 0.f, 0.f};
    bf16x8 a[4][2], b[4][2];

    // ---- prologue: tile0 (8 loads) -> buf0; tile1 partial (6 loads) -> buf1 ----
    STG_A(0, 0, 0); STG_A(1, 0, 0); STG_A(2, 0, 0); STG_A(3, 0, 0);
    STG_B(0, 0, 0); STG_B(1, 0, 0); STG_B(2, 0, 0); STG_B(3, 0, 0);
    STG_A(0, 1, 65536); STG_A(2, 1, 65536);
    STG_B(0, 1, 65536); STG_B(1, 1, 65536); STG_B(2, 1, 65536); STG_B(3, 1, 65536);
    asm volatile("s_waitcnt vmcnt(6)");
    __builtin_amdgcn_s_barrier();

    for (int i = 0; i < 6; ++i) {
        int ktE = 2 * i, ktO = 2 * i + 1;
        int s2 = (i < 5);
        // ===== even tile (buf0) =====
        // ph0
        LD_A(0, 0); LD_B(0, 0);
        STG_A(1, ktO, 65536); STG_A(3, ktO, 65536);
        PH_MID(); MFMAQ(0, 0); PH_END();
        // ph1
        LD_B(1, 0);
        if (s2) { STG_A(0, ktE + 2, 0); STG_A(2, ktE + 2, 0); }
        PH_MID(); MFMAQ(0, 1); PH_END();
        // ph2
        LD_A(1, 0);
        if (s2) { STG_B(0, ktE + 2, 0); STG_B(1, ktE + 2, 0); }
        PH_MID(); MFMAQ(1, 1); PH_END();
        // ph3
        if (s2) { STG_B(2, ktE + 2, 0); STG_B(3, ktE + 2, 0); }
        PH_MID(); MFMAQ(1, 0);
        __builtin_amdgcn_s_setprio(0);
        if (s2) { asm volatile("s_waitcnt vmcnt(6)"); }
        else    { asm volatile("s_waitcnt vmcnt(0)"); }
        __builtin_amdgcn_s_barrier();
        // ===== odd tile (buf1) =====
        // ph4
        LD_A(0, 65536); LD_B(0, 65536);
        if (s2) { STG_A(1, ktE + 2, 0); STG_A(3, ktE + 2, 0); }
        PH_MID(); MFMAQ(0, 0); PH_END();
        // ph5
        LD_B(1, 65536);
        if (s2) { STG_A(0, ktO + 2, 65536); STG_A(2, ktO + 2, 65536); }
        PH_MID(); MFMAQ(0, 1); PH_END();
        // ph6
        LD_A(1, 65536);
        if (s2) { STG_B(0, ktO + 2, 65536); STG_B(1, ktO + 2, 65536); }
        PH_MID(); MFMAQ(1, 1); PH_END();
        // ph7
        if (s2) { STG_B(2, ktO + 2, 65536); STG_B(3, ktO + 2, 65536); }
        PH_MID(); MFMAQ(1, 0);
        __builtin_amdgcn_s_setprio(0);
        if (s2) { asm volatile("s_waitcnt vmcnt(6)"); }
        __builtin_amdgcn_s_barrier();
    }

    // epilogue: C/D layout col=lane&15, row=4*(lane>>4)+reg
#pragma unroll
    for (int m = 0; m < 8; ++m) {
        int gr0 = m0 + wr * 128 + m * 16 + lk * 4;
#pragma unroll
        for (int n = 0; n < 4; ++n) {
            int gc = n0 + wc * 64 + n * 16 + lr;
            float bv = bias[gc];
#pragma unroll
            for (int r = 0; r < 4; ++r) {
                int gr = gr0 + r;
                float v = acc[m][n][r] + bv;
                if (MODE == 0) {
                    outBf[(size_t)gr * ldoBf + gc] = f2bf(v);
                } else {
                    v += bf2f(resid[(size_t)gr * ldr + gc]);
                    outF[(size_t)gr * DMODEL + gc] = v;
                }
            }
        }
    }
}

// ---------------- qfs logits: [M,16(12)] = q @ Wqa^T ----------------
__global__ __launch_bounds__(256) void qfs_kernel(
    const unsigned short* __restrict__ q, int ldq,
    const unsigned short* __restrict__ wqa,
    const float* __restrict__ bqa,
    const float* __restrict__ mask,
    float* __restrict__ qfs)
{
    int t = threadIdx.x;
    int w = t >> 6, lane = t & 63;
    int lr = lane & 15, lk = lane >> 4;
    int m0 = blockIdx.x * 64 + w * 16;

    f32x4 acc = (f32x4){0.f, 0.f, 0.f, 0.f};
    for (int k0 = 0; k0 < DMODEL; k0 += 32) {
        bf16x8 av = *(const bf16x8*)&q[(size_t)(m0 + lr) * ldq + k0 + lk * 8];
        bf16x8 bv = *(const bf16x8*)&wqa[lr * DMODEL + k0 + lk * 8];
        acc = __builtin_amdgcn_mfma_f32_16x16x32_bf16(av, bv, acc, 0, 0, 0);
    }
    if (lr < NH) {
        float bv = bqa[lr];
#pragma unroll
        for (int r = 0; r < 4; ++r) {
            int m = m0 + lk * 4 + r;
            int b_ = m >> 12;
            int s = m & (S_LEN - 1);
            qfs[((size_t)b_ * NH + lr) * S_LEN + s] = acc[r] * INV_SQRT_DH + bv + mask[b_ * S_LEN + s];
        }
    }
}

// ---------------- softmax-pool ----------------
__global__ __launch_bounds__(1024) void pool_kernel(
    const float* __restrict__ logits,
    const unsigned short* __restrict__ x, int ldx,
    float* __restrict__ pooled)
{
    int bh = blockIdx.x;
    int b = bh / NH, h = bh % NH;
    const float* lg = logits + (size_t)bh * S_LEN;
    int t = threadIdx.x;

    __shared__ float redm[16];
    __shared__ float reds[16];
    __shared__ float part[16][64];

    float mx = -1e30f;
    for (int s = t; s < S_LEN; s += 1024) mx = fmaxf(mx, lg[s]);
#pragma unroll
    for (int off = 32; off; off >>= 1) mx = fmaxf(mx, __shfl_xor(mx, off));
    if ((t & 63) == 0) redm[t >> 6] = mx;
    __syncthreads();
    float bmax = redm[0];
#pragma unroll
    for (int i = 1; i < 16; ++i) bmax = fmaxf(bmax, redm[i]);

    float sm = 0.f;
    for (int s = t; s < S_LEN; s += 1024) sm += __expf(lg[s] - bmax);
#pragma unroll
    for (int off = 32; off; off >>= 1) sm += __shfl_xor(sm, off);
    if ((t & 63) == 0) reds[t >> 6] = sm;
    __syncthreads();
    float bsum = 0.f;
#pragma unroll
    for (int i = 0; i < 16; ++i) bsum += reds[i];

    int d = t & 63, g = t >> 6;
    const unsigned short* xp = x + (size_t)b * S_LEN * ldx + h * DHEAD + d;
    float acc = 0.f;
    for (int s = g; s < S_LEN; s += 16)
        acc += __expf(lg[s] - bmax) * bf2f(xp[(size_t)s * ldx]);
    part[g][d] = acc;
    __syncthreads();
    if (t < 64) {
        float v = 0.f;
#pragma unroll
        for (int i = 0; i < 16; ++i) v += part[i][t];
        pooled[(size_t)bh * DHEAD + t] = v / bsum;
    }
}

// ---------------- qks logits ----------------
__global__ __launch_bounds__(256) void qks_kernel(
    const unsigned short* __restrict__ kmat, int ldk,
    const float* __restrict__ pooled_q,
    const float* __restrict__ mask,
    float* __restrict__ qks)
{
    int b = blockIdx.y;
    int s0 = blockIdx.x * 16;
    __shared__ float pq[NH][DHEAD + 4];
    int t = threadIdx.x;
    for (int i = t; i < NH * DHEAD; i += 256)
        pq[i >> 6][i & 63] = pooled_q[(size_t)b * NH * DHEAD + i];
    __syncthreads();
    int h = t & 15, sl = t >> 4;
    if (h < NH) {
        int s = s0 + sl;
        const unsigned short* kp = kmat + (size_t)(b * S_LEN + s) * ldk + h * DHEAD;
        float acc = 0.f;
#pragma unroll
        for (int c = 0; c < 8; ++c) {
            bf16x8 v = *(const bf16x8*)&kp[c * 8];
#pragma unroll
            for (int j = 0; j < 8; ++j)
                acc += bf2f((unsigned short)v[j]) * pq[h][c * 8 + j];
        }
        qks[((size_t)b * NH + h) * S_LEN + s] = acc * INV_SQRT_DH + mask[b * S_LEN + s];
    }
}

// ---------------- gate ----------------
__global__ __launch_bounds__(256) void gate_kernel(
    const unsigned short* __restrict__ q, int ldq,
    const float* __restrict__ pooled_k,
    unsigned short* __restrict__ gq)
{
    int i = blockIdx.x * blockDim.x + threadIdx.x;
    int m = i / (DMODEL / 8);
    int kc = (i % (DMODEL / 8)) * 8;
    int b = m >> 12;
    int h = kc >> 6;
    bf16x8 v = *(const bf16x8*)&q[(size_t)m * ldq + kc];
    const float* pk = pooled_k + ((size_t)b * NH + h) * DHEAD + (kc & 63);
    bf16x8 o;
#pragma unroll
    for (int j = 0; j < 8; ++j)
        o[j] = (short)f2bf(bf2f((unsigned short)v[j]) * pk[j]);
    *(bf16x8*)&gq[(size_t)m * DMODEL + kc] = o;
}

// ---------------- launch ----------------
extern "C" void kernel_launch(void* const* d_in, const int* in_sizes, int n_in,
                              void* d_out, int out_size, void* d_ws, size_t ws_size,
                              hipStream_t stream) {
    const float* hs   = (const float*)d_in[0];
    const float* mask = (const float*)d_in[1];
    const float* Wq   = (const float*)d_in[2];
    const float* bq   = (const float*)d_in[3];
    const float* Wqa  = (const float*)d_in[4];
    const float* bqa  = (const float*)d_in[5];
    const float* Wk   = (const float*)d_in[6];
    const float* bk   = (const float*)d_in[7];
    const float* Wt   = (const float*)d_in[8];
    const float* bt   = (const float*)d_in[9];
    float* out = (float*)d_out;

    char* ws = (char*)d_ws;
    unsigned short* qk_bf  = (unsigned short*)(ws);                   // [32768][1536] bf16 (q|k)
    unsigned short* hs_bf  = (unsigned short*)(ws + 100663296);       // [32768][768]  (reused as gq)
    unsigned short* Wqk_bf = (unsigned short*)(ws + 150994944);       // [1536][768]
    unsigned short* Wt_bf  = (unsigned short*)(ws + 153354240);       // [768][768]
    unsigned short* Wqa_bf = (unsigned short*)(ws + 154533888);       // [16][768]
    float* bqk      = (float*)(ws + 154558464);                       // [1536]
    float* qfs      = (float*)(ws + 154564608);                       // [96][4096]
    float* qks      = (float*)(ws + 156137472);                       // [96][4096]
    float* pooled_q = (float*)(ws + 157710336);                       // [96][64]
    float* pooled_k = (float*)(ws + 157734912);                       // [96][64]

    int nHs = M_TOT * DMODEL;

    cvt_f32_bf16<<<nHs / 1024, 256, 0, stream>>>(hs, hs_bf, nHs);
    prep_misc<<<1742, 256, 0, stream>>>(Wq, Wk, Wt, Wqa, bq, bk, Wqk_bf, Wt_bf, Wqa_bf, bqk);

    // q|k projection: M=32768, N=1536, K=768
    gemm8<0><<<(M_TOT / 256) * 6, 512, 0, stream>>>(
        hs_bf, Wqk_bf, bqk, qk_bf, 2 * DMODEL, nullptr, nullptr, 0, 6);

    qfs_kernel<<<M_TOT / 64, 256, 0, stream>>>(qk_bf, 2 * DMODEL, Wqa_bf, bqa, mask, qfs);
    pool_kernel<<<NB * NH, 1024, 0, stream>>>(qfs, qk_bf, 2 * DMODEL, pooled_q);
    qks_kernel<<<dim3(S_LEN / 16, NB), 256, 0, stream>>>(qk_bf + DMODEL, 2 * DMODEL, pooled_q, mask, qks);
    pool_kernel<<<NB * NH, 1024, 0, stream>>>(qks, qk_bf + DMODEL, 2 * DMODEL, pooled_k);

    unsigned short* gq = hs_bf;
    gate_kernel<<<(M_TOT * (DMODEL / 8)) / 256, 256, 0, stream>>>(qk_bf, 2 * DMODEL, pooled_k, gq);

    // out = gq @ Wt^T + bt + q : M=32768, N=768, K=768
    gemm8<1><<<(M_TOT / 256) * 3, 512, 0, stream>>>(
        gq, Wt_bf, bt, nullptr, 0, out, qk_bf, 2 * DMODEL, 3);
}

// Round 3
// 222.529 us; speedup vs baseline: 2.1573x; 1.6996x over previous
//
#include <hip/hip_runtime.h>
#include <cstdint>
#include <cstddef>

#define S_LEN 4096
#define NB 8
#define NH 12
#define DMODEL 768
#define DHEAD 64
#define M_TOT (NB * S_LEN)      /* 32768 */
#define INV_SQRT_DH 0.125f
#define WSZ (DMODEL * DMODEL)

typedef __attribute__((ext_vector_type(4))) float f32x4;
typedef __attribute__((ext_vector_type(8))) short bf16x8;

__device__ inline float bf2f(unsigned short h) {
    union { unsigned int u; float f; } v; v.u = ((unsigned int)h) << 16; return v.f;
}
__device__ inline unsigned short f2bf(float f) {
    union { float f; unsigned int u; } v; v.f = f;
    unsigned int r = v.u + 0x7FFFu + ((v.u >> 16) & 1u);
    return (unsigned short)(r >> 16);
}

__device__ inline void gload_lds16(const unsigned short* gp, void* lp) {
    __builtin_amdgcn_global_load_lds((const __attribute__((address_space(1))) void*)gp,
                                     (__attribute__((address_space(3))) void*)lp,
                                     16, 0, 0);
}

// ---------------- prep: hs cvt + all weights/biases, one launch ----------------
__global__ void prep_all(const float* __restrict__ hs,
                         const float* __restrict__ Wq, const float* __restrict__ Wk,
                         const float* __restrict__ Wt, const float* __restrict__ Wqa,
                         const float* __restrict__ bq, const float* __restrict__ bk,
                         unsigned short* __restrict__ hs_bf,
                         unsigned short* __restrict__ Wqk_bf, unsigned short* __restrict__ Wt_bf,
                         unsigned short* __restrict__ Wqa_bf, float* __restrict__ bqk) {
    int bid = blockIdx.x;
    int t = threadIdx.x;
    if (bid < 24576) {
        int off = bid * 1024 + t * 4;
        float4 v = *(const float4*)(hs + off);
        ushort4 o;
        o.x = f2bf(v.x); o.y = f2bf(v.y); o.z = f2bf(v.z); o.w = f2bf(v.w);
        *(ushort4*)(hs_bf + off) = o;
        return;
    }
    bid -= 24576;
    if (bid < 1728) {
        const float* src = (bid < 576) ? Wq : ((bid < 1152) ? Wk : Wt);
        unsigned short* dst = (bid < 576) ? Wqk_bf : ((bid < 1152) ? (Wqk_bf + WSZ) : Wt_bf);
        int off = (bid % 576) * 1024 + t * 4;
        float4 v = *(const float4*)(src + off);
        ushort4 o;
        o.x = f2bf(v.x); o.y = f2bf(v.y); o.z = f2bf(v.z); o.w = f2bf(v.w);
        *(ushort4*)(dst + off) = o;
    } else if (bid < 1740) {
        int off = (bid - 1728) * 1024 + t * 4;   // 16*768 elems
        int h = off / DMODEL;
        ushort4 o = {0, 0, 0, 0};
        if (h < NH) {
            float4 v = *(const float4*)(Wqa + off);
            o.x = f2bf(v.x); o.y = f2bf(v.y); o.z = f2bf(v.z); o.w = f2bf(v.w);
        }
        *(ushort4*)(Wqa_bf + off) = o;
    } else {
        int off = (bid - 1740) * 1024 + t * 4;
        if (off < 2 * DMODEL) {
            const float* src = (off < DMODEL) ? (bq + off) : (bk + off - DMODEL);
            *(float4*)(bqk + off) = *(const float4*)src;
        }
    }
}

// ---------------- 256x256 8-phase GEMM ----------------
#define PH_MID() do { __builtin_amdgcn_s_barrier(); \
    asm volatile("s_waitcnt lgkmcnt(0)"); \
    __builtin_amdgcn_sched_barrier(0); \
    __builtin_amdgcn_s_setprio(1); } while (0)
#define PH_END() do { __builtin_amdgcn_s_setprio(0); \
    __builtin_amdgcn_s_barrier(); } while (0)

#define STG_A(q, kt, BO) gload_lds16(pA + (size_t)((q) * 64) * lda + (kt) * 64, \
                                     lds + (BO) + (q) * 8192 + wOff)
#define STG_B(q, kt, BO) gload_lds16(pB + (size_t)((q) * 64) * 768 + (kt) * 64, \
                                     lds + (BO) + 32768 + (q) * 8192 + wOff)

#define LD_A(mh, BO) do { _Pragma("unroll") for (int mm = 0; mm < 4; ++mm) { \
    a[mm][0] = *(const bf16x8*)(lds + (BO) + aRd0 + ((mh) * 4 + mm) * 2048); \
    a[mm][1] = *(const bf16x8*)(lds + (BO) + aRd1 + ((mh) * 4 + mm) * 2048); } } while (0)
#define LD_B(nh, BO) do { _Pragma("unroll") for (int nn = 0; nn < 2; ++nn) { \
    b[(nh) * 2 + nn][0] = *(const bf16x8*)(lds + (BO) + bRd0 + ((nh) * 2 + nn) * 2048); \
    b[(nh) * 2 + nn][1] = *(const bf16x8*)(lds + (BO) + bRd1 + ((nh) * 2 + nn) * 2048); } } while (0)
#define MFMAQ(mh, nh) do { _Pragma("unroll") for (int mm = 0; mm < 4; ++mm) \
    _Pragma("unroll") for (int nn = 0; nn < 2; ++nn) { \
        acc[(mh) * 4 + mm][(nh) * 2 + nn] = __builtin_amdgcn_mfma_f32_16x16x32_bf16( \
            a[mm][0], b[(nh) * 2 + nn][0], acc[(mh) * 4 + mm][(nh) * 2 + nn], 0, 0, 0); \
        acc[(mh) * 4 + mm][(nh) * 2 + nn] = __builtin_amdgcn_mfma_f32_16x16x32_bf16( \
            a[mm][1], b[(nh) * 2 + nn][1], acc[(mh) * 4 + mm][(nh) * 2 + nn], 0, 0, 0); } } while (0)

// MODE0: bf16 out (qk proj). MODE1: f32 out + resid, B selected per batch (gated Wt).
template<int MODE>
__global__ __launch_bounds__(512, 2) void gemm8(
    const unsigned short* __restrict__ A, int lda,
    const unsigned short* __restrict__ Bw,
    const float* __restrict__ bias,
    unsigned short* __restrict__ outBf, int ldoBf,
    float* __restrict__ outF,
    const unsigned short* __restrict__ resid, int ldr,
    int ntn)
{
    __shared__ __align__(16) char lds[131072];

    int nwg = gridDim.x;
    int bid = blockIdx.x;
    int cpx = nwg >> 3;
    int swz = (bid & 7) * cpx + (bid >> 3);
    int bidn = swz % ntn, bidm = swz / ntn;
    int m0 = bidm * 256, n0 = bidn * 256;

    if (MODE == 1) Bw += (size_t)(m0 >> 12) * WSZ;   // per-batch gated Wt

    int t = threadIdx.x;
    int w = t >> 6, lane = t & 63;
    int lr = lane & 15, lk = lane >> 4;
    int wr = w >> 2, wc = w & 3;
    int wOff = w << 10;

    int srow = t >> 3;
    int sblk = (t & 7) ^ (srow & 7);
    const unsigned short* pA = A + (size_t)(m0 + srow) * lda + sblk * 8;
    const unsigned short* pB = Bw + (size_t)(n0 + srow) * 768 + sblk * 8;

    int sx = lr & 7;
    int aRd0 = (wr * 128 + lr) * 128 + ((0 + lk) ^ sx) * 16;
    int aRd1 = (wr * 128 + lr) * 128 + ((4 + lk) ^ sx) * 16;
    int bRd0 = 32768 + (wc * 64 + lr) * 128 + ((0 + lk) ^ sx) * 16;
    int bRd1 = 32768 + (wc * 64 + lr) * 128 + ((4 + lk) ^ sx) * 16;

    f32x4 acc[8][4];
#pragma unroll
    for (int m = 0; m < 8; ++m)
#pragma unroll
        for (int n = 0; n < 4; ++n)
            acc[m][n] = (f32x4){0.f, 0.f, 0.f, 0.f};
    bf16x8 a[4][2], b[4][2];

    STG_A(0, 0, 0); STG_A(1, 0, 0); STG_A(2, 0, 0); STG_A(3, 0, 0);
    STG_B(0, 0, 0); STG_B(1, 0, 0); STG_B(2, 0, 0); STG_B(3, 0, 0);
    STG_A(0, 1, 65536); STG_A(2, 1, 65536);
    STG_B(0, 1, 65536); STG_B(1, 1, 65536); STG_B(2, 1, 65536); STG_B(3, 1, 65536);
    asm volatile("s_waitcnt vmcnt(6)");
    __builtin_amdgcn_s_barrier();

    for (int i = 0; i < 6; ++i) {
        int ktE = 2 * i, ktO = 2 * i + 1;
        int s2 = (i < 5);
        // ===== even tile (buf0) =====
        LD_A(0, 0); LD_B(0, 0);
        STG_A(1, ktO, 65536); STG_A(3, ktO, 65536);
        PH_MID(); MFMAQ(0, 0); PH_END();
        LD_B(1, 0);
        if (s2) { STG_A(0, ktE + 2, 0); STG_A(2, ktE + 2, 0); }
        PH_MID(); MFMAQ(0, 1); PH_END();
        LD_A(1, 0);
        if (s2) { STG_B(0, ktE + 2, 0); STG_B(1, ktE + 2, 0); }
        PH_MID(); MFMAQ(1, 1); PH_END();
        if (s2) { STG_B(2, ktE + 2, 0); STG_B(3, ktE + 2, 0); }
        PH_MID(); MFMAQ(1, 0);
        __builtin_amdgcn_s_setprio(0);
        if (s2) { asm volatile("s_waitcnt vmcnt(6)"); }
        else    { asm volatile("s_waitcnt vmcnt(0)"); }
        __builtin_amdgcn_s_barrier();
        // ===== odd tile (buf1) =====
        LD_A(0, 65536); LD_B(0, 65536);
        if (s2) { STG_A(1, ktE + 2, 0); STG_A(3, ktE + 2, 0); }
        PH_MID(); MFMAQ(0, 0); PH_END();
        LD_B(1, 65536);
        if (s2) { STG_A(0, ktO + 2, 65536); STG_A(2, ktO + 2, 65536); }
        PH_MID(); MFMAQ(0, 1); PH_END();
        LD_A(1, 65536);
        if (s2) { STG_B(0, ktO + 2, 65536); STG_B(1, ktO + 2, 65536); }
        PH_MID(); MFMAQ(1, 1); PH_END();
        if (s2) { STG_B(2, ktO + 2, 65536); STG_B(3, ktO + 2, 65536); }
        PH_MID(); MFMAQ(1, 0);
        __builtin_amdgcn_s_setprio(0);
        if (s2) { asm volatile("s_waitcnt vmcnt(6)"); }
        __builtin_amdgcn_s_barrier();
    }

#pragma unroll
    for (int m = 0; m < 8; ++m) {
        int gr0 = m0 + wr * 128 + m * 16 + lk * 4;
#pragma unroll
        for (int n = 0; n < 4; ++n) {
            int gc = n0 + wc * 64 + n * 16 + lr;
            float bv = bias[gc];
#pragma unroll
            for (int r = 0; r < 4; ++r) {
                int gr = gr0 + r;
                float v = acc[m][n][r] + bv;
                if (MODE == 0) {
                    outBf[(size_t)gr * ldoBf + gc] = f2bf(v);
                } else {
                    v += bf2f(resid[(size_t)gr * ldr + gc]);
                    outF[(size_t)gr * DMODEL + gc] = v;
                }
            }
        }
    }
}

// ---------------- qfs logits: [M,16(12)] = q @ Wqa^T ----------------
__global__ __launch_bounds__(256) void qfs_kernel(
    const unsigned short* __restrict__ q, int ldq,
    const unsigned short* __restrict__ wqa,
    const float* __restrict__ bqa,
    const float* __restrict__ mask,
    float* __restrict__ qfs)
{
    int t = threadIdx.x;
    int w = t >> 6, lane = t & 63;
    int lr = lane & 15, lk = lane >> 4;
    int m0 = blockIdx.x * 64 + w * 16;

    f32x4 acc = (f32x4){0.f, 0.f, 0.f, 0.f};
    for (int k0 = 0; k0 < DMODEL; k0 += 32) {
        bf16x8 av = *(const bf16x8*)&q[(size_t)(m0 + lr) * ldq + k0 + lk * 8];
        bf16x8 bv = *(const bf16x8*)&wqa[lr * DMODEL + k0 + lk * 8];
        acc = __builtin_amdgcn_mfma_f32_16x16x32_bf16(av, bv, acc, 0, 0, 0);
    }
    if (lr < NH) {
        float bv = bqa[lr];
#pragma unroll
        for (int r = 0; r < 4; ++r) {
            int m = m0 + lk * 4 + r;
            int b_ = m >> 12;
            int s = m & (S_LEN - 1);
            qfs[((size_t)b_ * NH + lr) * S_LEN + s] = acc[r] * INV_SQRT_DH + bv + mask[b_ * S_LEN + s];
        }
    }
}

// ---------------- chunked softmax-pool over precomputed logits (pool1) ----------------
// grid = 96*8; block (bh, c) handles s in [c*512, c*512+512).
// parts[bh][c][0..63] = sum_s exp(l-m_c)*x[s,d]; [64]=m_c; [65]=Z_c
__global__ __launch_bounds__(256) void pool1_kernel(
    const float* __restrict__ logits,          // [96][4096]
    const unsigned short* __restrict__ qk,     // ld 1536
    float* __restrict__ parts)                 // [96][8][72]
{
    int bid = blockIdx.x;
    int bh = bid >> 3, c = bid & 7;
    int b = bh / NH, h = bh % NH;
    int s0 = c * 512;
    int t = threadIdx.x;

    __shared__ float w[512];
    __shared__ float red[8];
    __shared__ float part[4][64];

    const float* lg = logits + (size_t)bh * S_LEN + s0;
    float l0 = lg[t], l1 = lg[t + 256];
    float m = fmaxf(l0, l1);
#pragma unroll
    for (int off = 32; off; off >>= 1) m = fmaxf(m, __shfl_xor(m, off));
    if ((t & 63) == 0) red[t >> 6] = m;
    __syncthreads();
    float M = fmaxf(fmaxf(red[0], red[1]), fmaxf(red[2], red[3]));
    float w0 = __expf(l0 - M), w1 = __expf(l1 - M);
    w[t] = w0; w[t + 256] = w1;
    float z = w0 + w1;
#pragma unroll
    for (int off = 32; off; off >>= 1) z += __shfl_xor(z, off);
    if ((t & 63) == 0) red[4 + (t >> 6)] = z;
    __syncthreads();
    float Z = red[4] + red[5] + red[6] + red[7];

    // weighted pass: direct global b128 reads
    int dblk = t & 7, rgrp = t >> 3;
    const unsigned short* xp = qk + ((size_t)(b * S_LEN + s0)) * 1536 + h * DHEAD + dblk * 8;
    float acc[8];
#pragma unroll
    for (int e = 0; e < 8; ++e) acc[e] = 0.f;
    for (int j = 0; j < 16; ++j) {
        int r = j * 32 + rgrp;
        bf16x8 v = *(const bf16x8*)(xp + (size_t)r * 1536);
        float wr = w[r];
#pragma unroll
        for (int e = 0; e < 8; ++e) acc[e] += wr * bf2f((unsigned short)v[e]);
    }
#pragma unroll
    for (int off = 8; off <= 32; off <<= 1)
#pragma unroll
        for (int e = 0; e < 8; ++e) acc[e] += __shfl_xor(acc[e], off);
    if ((t & 63) < 8) {
#pragma unroll
        for (int e = 0; e < 8; ++e) part[t >> 6][(t & 7) * 8 + e] = acc[e];
    }
    __syncthreads();
    float* dst = parts + ((size_t)bh * 8 + c) * 72;
    if (t < 64) dst[t] = part[0][t] + part[1][t] + part[2][t] + part[3][t];
    else if (t == 64) dst[64] = M;
    else if (t == 65) dst[65] = Z;
}

// ---------------- fused qks+pool2: merge pooled_q, compute k logits, chunked pool ----------------
__global__ __launch_bounds__(256) void pool2_kernel(
    const float* __restrict__ parts1,          // [96][8][72]
    const unsigned short* __restrict__ qk,     // ld 1536, k at col offset 768
    const float* __restrict__ mask,
    float* __restrict__ parts2)                // [96][8][72]
{
    int bid = blockIdx.x;
    int bh = bid >> 3, c = bid & 7;
    int b = bh / NH, h = bh % NH;
    int s0 = c * 512;
    int t = threadIdx.x;

    __shared__ float pq[64];
    __shared__ float w[512];
    __shared__ float red[8];
    __shared__ float part[4][64];

    // merge pooled_q from parts1
    if (t < 64) {
        const float* p1 = parts1 + (size_t)bh * 8 * 72;
        float M1 = -1e30f;
#pragma unroll
        for (int cc = 0; cc < 8; ++cc) M1 = fmaxf(M1, p1[cc * 72 + 64]);
        float Z1 = 0.f, a1 = 0.f;
#pragma unroll
        for (int cc = 0; cc < 8; ++cc) {
            float f = __expf(p1[cc * 72 + 64] - M1);
            Z1 += f * p1[cc * 72 + 65];
            a1 += f * p1[cc * 72 + t];
        }
        pq[t] = a1 / Z1;
    }
    __syncthreads();

    int dblk = t & 7, rgrp = t >> 3;
    float pq8[8];
#pragma unroll
    for (int e = 0; e < 8; ++e) pq8[e] = pq[dblk * 8 + e];

    const unsigned short* kp = qk + ((size_t)(b * S_LEN + s0)) * 1536 + DMODEL + h * DHEAD + dblk * 8;

    // dot pass -> logits in w[]
    for (int j = 0; j < 16; ++j) {
        int r = j * 32 + rgrp;
        bf16x8 v = *(const bf16x8*)(kp + (size_t)r * 1536);
        float d = 0.f;
#pragma unroll
        for (int e = 0; e < 8; ++e) d += bf2f((unsigned short)v[e]) * pq8[e];
        d += __shfl_xor(d, 1); d += __shfl_xor(d, 2); d += __shfl_xor(d, 4);
        if (dblk == 0) w[r] = d * INV_SQRT_DH + mask[b * S_LEN + s0 + r];
    }
    __syncthreads();

    // softmax over w[512]
    float l0 = w[t], l1 = w[t + 256];
    float m = fmaxf(l0, l1);
#pragma unroll
    for (int off = 32; off; off >>= 1) m = fmaxf(m, __shfl_xor(m, off));
    if ((t & 63) == 0) red[t >> 6] = m;
    __syncthreads();
    float M = fmaxf(fmaxf(red[0], red[1]), fmaxf(red[2], red[3]));
    float w0 = __expf(l0 - M), w1 = __expf(l1 - M);
    float z = w0 + w1;
#pragma unroll
    for (int off = 32; off; off >>= 1) z += __shfl_xor(z, off);
    if ((t & 63) == 0) red[4 + (t >> 6)] = z;
    __syncthreads();
    w[t] = w0; w[t + 256] = w1;
    __syncthreads();
    float Z = red[4] + red[5] + red[6] + red[7];

    // weighted pass (k re-read, L2-hot)
    float acc[8];
#pragma unroll
    for (int e = 0; e < 8; ++e) acc[e] = 0.f;
    for (int j = 0; j < 16; ++j) {
        int r = j * 32 + rgrp;
        bf16x8 v = *(const bf16x8*)(kp + (size_t)r * 1536);
        float wr = w[r];
#pragma unroll
        for (int e = 0; e < 8; ++e) acc[e] += wr * bf2f((unsigned short)v[e]);
    }
#pragma unroll
    for (int off = 8; off <= 32; off <<= 1)
#pragma unroll
        for (int e = 0; e < 8; ++e) acc[e] += __shfl_xor(acc[e], off);
    if ((t & 63) < 8) {
#pragma unroll
        for (int e = 0; e < 8; ++e) part[t >> 6][(t & 7) * 8 + e] = acc[e];
    }
    __syncthreads();
    float* dst = parts2 + ((size_t)bh * 8 + c) * 72;
    if (t < 64) dst[t] = part[0][t] + part[1][t] + part[2][t] + part[3][t];
    else if (t == 64) dst[64] = M;
    else if (t == 65) dst[65] = Z;
}

// ---------------- gated weights: W8[b] = Wt * pooled_k[b][col] ----------------
// grid = 8*96; block (b, rg) covers rows [rg*8, rg*8+8)
__global__ __launch_bounds__(256) void gatedw_kernel(
    const float* __restrict__ parts2,
    const unsigned short* __restrict__ Wt_bf,
    unsigned short* __restrict__ W8)
{
    int bid = blockIdx.x;
    int b = bid / 96, rg = bid % 96;
    int t = threadIdx.x;

    __shared__ float mhc[96], Mh[12], fac[96], zh[12], pk[768];

    if (t < 96) mhc[t] = parts2[((size_t)(b * NH + t / 8) * 8 + (t & 7)) * 72 + 64];
    __syncthreads();
    if (t < 12) {
        float M = -1e30f;
#pragma unroll
        for (int cc = 0; cc < 8; ++cc) M = fmaxf(M, mhc[t * 8 + cc]);
        Mh[t] = M;
    }
    __syncthreads();
    if (t < 96) fac[t] = __expf(mhc[t] - Mh[t / 8]);
    __syncthreads();
    if (t < 12) {
        float Zm = 0.f;
#pragma unroll
        for (int cc = 0; cc < 8; ++cc)
            Zm += fac[t * 8 + cc] * parts2[((size_t)(b * NH + t) * 8 + cc) * 72 + 65];
        zh[t] = Zm;
    }
    __syncthreads();
#pragma unroll
    for (int j = 0; j < 3; ++j) {
        int col = t + 256 * j;
        int h = col >> 6, d = col & 63;
        const float* p2 = parts2 + (size_t)(b * NH + h) * 8 * 72;
        float v = 0.f;
#pragma unroll
        for (int cc = 0; cc < 8; ++cc) v += fac[h * 8 + cc] * p2[cc * 72 + d];
        pk[col] = v / zh[h];
    }
    __syncthreads();
#pragma unroll
    for (int j = 0; j < 3; ++j) {
        int idx = j * 2048 + t * 8;
        int r = rg * 8 + idx / DMODEL, k = idx % DMODEL;
        bf16x8 wv = *(const bf16x8*)(Wt_bf + (size_t)r * DMODEL + k);
        bf16x8 o;
#pragma unroll
        for (int e = 0; e < 8; ++e)
            o[e] = (short)f2bf(bf2f((unsigned short)wv[e]) * pk[k + e]);
        *(bf16x8*)(W8 + (size_t)b * WSZ + (size_t)r * DMODEL + k) = o;
    }
}

// ---------------- launch ----------------
extern "C" void kernel_launch(void* const* d_in, const int* in_sizes, int n_in,
                              void* d_out, int out_size, void* d_ws, size_t ws_size,
                              hipStream_t stream) {
    const float* hs   = (const float*)d_in[0];
    const float* mask = (const float*)d_in[1];
    const float* Wq   = (const float*)d_in[2];
    const float* bq   = (const float*)d_in[3];
    const float* Wqa  = (const float*)d_in[4];
    const float* bqa  = (const float*)d_in[5];
    const float* Wk   = (const float*)d_in[6];
    const float* bk   = (const float*)d_in[7];
    const float* Wt   = (const float*)d_in[8];
    const float* bt   = (const float*)d_in[9];
    float* out = (float*)d_out;

    char* ws = (char*)d_ws;
    unsigned short* qk_bf  = (unsigned short*)(ws);                   // [32768][1536] bf16
    unsigned short* hs_bf  = (unsigned short*)(ws + 100663296);       // [32768][768]; dead after gemm1
    unsigned short* W8     = hs_bf;                                   // overlays hs_bf: 8x[768][768]
    unsigned short* Wqk_bf = (unsigned short*)(ws + 150994944);       // [1536][768]
    unsigned short* Wt_bf  = (unsigned short*)(ws + 153354240);       // [768][768]
    unsigned short* Wqa_bf = (unsigned short*)(ws + 154533888);       // [16][768]
    float* bqk    = (float*)(ws + 154558464);                         // [1536]
    float* qfs    = (float*)(ws + 154564608);                         // [96][4096]
    float* parts1 = (float*)(ws + 156137472);                         // [96][8][72]
    float* parts2 = (float*)(ws + 156358656);                         // [96][8][72] (ends 156579840)

    prep_all<<<26318, 256, 0, stream>>>(hs, Wq, Wk, Wt, Wqa, bq, bk,
                                        hs_bf, Wqk_bf, Wt_bf, Wqa_bf, bqk);

    // q|k projection: M=32768, N=1536, K=768
    gemm8<0><<<(M_TOT / 256) * 6, 512, 0, stream>>>(
        hs_bf, DMODEL, Wqk_bf, bqk, qk_bf, 2 * DMODEL, nullptr, nullptr, 0, 6);

    qfs_kernel<<<M_TOT / 64, 256, 0, stream>>>(qk_bf, 2 * DMODEL, Wqa_bf, bqa, mask, qfs);

    pool1_kernel<<<NB * NH * 8, 256, 0, stream>>>(qfs, qk_bf, parts1);
    pool2_kernel<<<NB * NH * 8, 256, 0, stream>>>(parts1, qk_bf, mask, parts2);
    gatedw_kernel<<<NB * 96, 256, 0, stream>>>(parts2, Wt_bf, W8);

    // out = q @ (Wt*pk_b)^T + bt + q : M=32768, N=768, K=768
    gemm8<1><<<(M_TOT / 256) * 3, 512, 0, stream>>>(
        qk_bf, 2 * DMODEL, W8, bt, nullptr, 0, out, qk_bf, 2 * DMODEL, 3);
}